// Round 2
// baseline (489.541 us; speedup 1.0000x reference)
//
#include <hip/hip_runtime.h>
#include <hip/hip_bf16.h>

#define N 8192
#define FD 128
#define LOG2E 1.4426950408889634f

typedef __attribute__((ext_vector_type(4))) float f4;
typedef __attribute__((ext_vector_type(4))) int i32x4;
typedef __attribute__((ext_vector_type(4))) unsigned int u32x4;
typedef __attribute__((ext_vector_type(8))) __bf16 bf16x8;

__device__ __forceinline__ unsigned short bfbits(float x){
  __bf16 b = (__bf16)x;
  return __builtin_bit_cast(unsigned short, b);
}

// ---------------- K1: Wh = h @ W (f32), plus Bsw = Wh in MFMA-B-fragment order ----
// Bsw flat layout: elem(jblk, n, lane, e) at ((jblk*8+n)*64 + lane)*8 + e
//   holds bf16( Wh[jblk*32 + (lane>>4)*8 + e][n*16 + (lane&15)] )
// so k4's B-frag load for (jtile, n) is 64 lanes x 16B contiguous = 1KB coalesced.
__global__ __launch_bounds__(256) void k1_wh(const float* __restrict__ h,
                                             const float* __restrict__ W,
                                             float* __restrict__ Wh,
                                             unsigned short* __restrict__ Bsw){
  __shared__ float Wl[64*128];   // half of W (k-split), 32KB
  __shared__ float hT[128*33];   // h tile transposed [k][r], padded stride 33
  int t = threadIdx.x;
  int i0 = blockIdx.x * 32;
  {
    int r  = t >> 3;           // 0..31
    int k0 = (t & 7) * 16;     // 0,16,...,112
    const f4* src = (const f4*)&h[(size_t)(i0 + r)*FD + k0];
    #pragma unroll
    for (int q = 0; q < 4; ++q){
      f4 v = src[q];
      #pragma unroll
      for (int e = 0; e < 4; ++e) hT[(k0 + q*4 + e)*33 + r] = v[e];
    }
  }
  int f0 = (t & 31) * 4;   // 0..124
  int r0 = (t >> 5) * 4;   // 0..28
  float acc[4][4] = {};
  for (int half = 0; half < 2; ++half){
    __syncthreads();
    #pragma unroll
    for (int v = 0; v < 8; ++v){
      int idx = (v*256 + t)*4;
      *(f4*)&Wl[idx] = *(const f4*)&W[half*8192 + idx];
    }
    __syncthreads();
    for (int k2 = 0; k2 < 64; ++k2){
      f4 wv = *(const f4*)&Wl[k2*FD + f0];
      f4 hv = *(const f4*)&hT[(half*64 + k2)*33 + r0];
      #pragma unroll
      for (int ri = 0; ri < 4; ++ri)
        #pragma unroll
        for (int fi = 0; fi < 4; ++fi)
          acc[ri][fi] = __builtin_fmaf(hv[ri], wv[fi], acc[ri][fi]);
    }
  }
  #pragma unroll
  for (int ri = 0; ri < 4; ++ri){
    f4 o = {acc[ri][0], acc[ri][1], acc[ri][2], acc[ri][3]};
    *(f4*)&Wh[(size_t)(i0 + r0 + ri)*FD + f0] = o;
  }
  // Bsw scatter-store (one-time cost, makes k4's hot loads coalesced)
  int jblk = blockIdx.x;
  int n  = f0 >> 4;        // feature block 0..7
  int fl = f0 & 15;        // feature-in-block 0,4,8,12
  #pragma unroll
  for (int ri = 0; ri < 4; ++ri){
    int k = r0 + ri;                       // row-in-tile 0..31 (the MFMA k index)
    size_t base = (((size_t)jblk*8 + n)*64 + ((k>>3)<<4))*8 + (k&7);
    #pragma unroll
    for (int fi = 0; fi < 4; ++fi)
      Bsw[base + (size_t)(fl + fi)*8] = bfbits(acc[ri][fi]);
  }
}

// ---------------- K2: s1L = (Wh@a1)*log2e, s2L = (Wh@a2)*log2e ----------------
__global__ __launch_bounds__(256) void k2_s(const float* __restrict__ Wh,
                                            const float* __restrict__ a,
                                            float* __restrict__ s1L,
                                            float* __restrict__ s2L){
  int i = blockIdx.x*256 + threadIdx.x;
  const f4* row = (const f4*)&Wh[(size_t)i*FD];
  const f4* a1 = (const f4*)a;
  const f4* a2 = (const f4*)&a[FD];
  float x1 = 0.f, x2 = 0.f;
  #pragma unroll
  for (int q = 0; q < 32; ++q){
    f4 w = row[q], va = a1[q], vb = a2[q];
    #pragma unroll
    for (int e = 0; e < 4; ++e){
      x1 = __builtin_fmaf(w[e], va[e], x1);
      x2 = __builtin_fmaf(w[e], vb[e], x2);
    }
  }
  s1L[i] = x1 * LOG2E; s2L[i] = x2 * LOG2E;
}

// ---------------- K3: M2L = max(s2L) ----------------
__global__ __launch_bounds__(256) void k3_max(const float* __restrict__ s2L,
                                              float* __restrict__ M2L){
  __shared__ float red[4];
  int t = threadIdx.x;
  float m = -3.0e38f;
  for (int i = t; i < N; i += 256) m = fmaxf(m, s2L[i]);
  #pragma unroll
  for (int d = 1; d < 64; d <<= 1) m = fmaxf(m, __shfl_xor(m, d, 64));
  if ((t & 63) == 0) red[t >> 6] = m;
  __syncthreads();
  if (t == 0) *M2L = fmaxf(fmaxf(red[0], red[1]), fmaxf(red[2], red[3]));
}

// ---------------- K4: fused masked-softmax numerator + denominator ----------------
// Wave handles 16 rows x full 128 features x one j-chunk. 4 waves/block share the
// j-range (L1 reuse of Bsw). No barriers, no LDS. Denominator = MFMA vs all-ones B.
// A-frag (16x16x32): row=lane&15, k=(lane>>4)*8+e.  C: col=lane&15, row=(lane>>4)*4+r.
__global__ __launch_bounds__(256,4) void k4_flash(const int* __restrict__ adj,
    const unsigned short* __restrict__ Bsw,
    const float* __restrict__ s1L, const float* __restrict__ s2L,
    const float* __restrict__ M2p,
    float* __restrict__ partial, float* __restrict__ denomp, int njc){
  int t = threadIdx.x;
  int wv = t >> 6, lane = t & 63;
  int lrow = lane & 15, lgrp = lane >> 4;
  int i0w = blockIdx.x * 64 + wv * 16;       // wave's first row
  int row = i0w + lrow;                      // this lane's A-frag row
  int jlen = N / njc;
  int jstart = blockIdx.y * jlen;
  int iters = jlen / 32;
  float M2 = *M2p;
  float s1a = s1L[row];
  float ea = s1a + M2;
  float maL = fmaxf(ea, 0.2f*ea);            // upper bound on row max (log2-space)

  f4 acc[8];
  #pragma unroll
  for (int n = 0; n < 8; ++n) acc[n] = (f4){0.f,0.f,0.f,0.f};
  f4 accd = (f4){0.f,0.f,0.f,0.f};

  u32x4 onesbits = (u32x4){0x3F803F80u,0x3F803F80u,0x3F803F80u,0x3F803F80u};
  bf16x8 ones = __builtin_bit_cast(bf16x8, onesbits);

  const i32x4* adj4 = (const i32x4*)adj;
  const f4* s2v = (const f4*)s2L;
  size_t rbase = ((size_t)row * N) >> 2;     // row base in i32x4 units

  int jb = jstart + lgrp*8;
  i32x4 c0 = adj4[rbase + (jb>>2)];
  i32x4 c1 = adj4[rbase + (jb>>2) + 1];
  f4 za = s2v[jb>>2], zb = s2v[(jb>>2)+1];

  for (int js = 0; js < iters; ++js){
    // rotate current tile into use-regs, issue next tile's loads immediately
    i32x4 u0 = c0, u1 = c1; f4 ya = za, yb = zb;
    int jn = jb + 32;
    if (jn >= jstart + jlen) jn = jstart + lgrp*8;   // safe dummy (branchless)
    c0 = adj4[rbase + (jn>>2)];
    c1 = adj4[rbase + (jn>>2) + 1];
    za = s2v[jn>>2]; zb = s2v[(jn>>2)+1];

    // B-frags: contiguous 1KB per load (pre-swizzled)
    int jtile = jb >> 5;   // uniform across wave (jb - lgrp*8 = jtile*32)
    u32x4 braw[8];
    #pragma unroll
    for (int n = 0; n < 8; ++n)
      braw[n] = *(const u32x4*)&Bsw[((((size_t)jtile*8 + n)*64) + lane)*8];

    bf16x8 fa;
    #pragma unroll
    for (int e = 0; e < 8; ++e){
      float sj = (e < 4) ? ya[e] : yb[e-4];
      int av   = (e < 4) ? u0[e] : u1[e-4];
      float x  = s1a + sj;
      float lr = fmaxf(x, 0.2f*x);
      float p  = av ? __builtin_amdgcn_exp2f(lr - maL) : 0.f;
      fa[e] = (__bf16)p;
    }
    accd = __builtin_amdgcn_mfma_f32_16x16x32_bf16(fa, ones, accd, 0, 0, 0);
    #pragma unroll
    for (int n = 0; n < 8; ++n)
      acc[n] = __builtin_amdgcn_mfma_f32_16x16x32_bf16(fa,
                 __builtin_bit_cast(bf16x8, braw[n]), acc[n], 0, 0, 0);
    jb += 32;
  }

  if (lrow == 0){
    #pragma unroll
    for (int r = 0; r < 4; ++r)
      denomp[(size_t)blockIdx.y*N + i0w + lgrp*4 + r] = accd[r];
  }
  float* pb = partial + (size_t)blockIdx.y * N * FD;
  #pragma unroll
  for (int n = 0; n < 8; ++n)
    #pragma unroll
    for (int r = 0; r < 4; ++r)
      pb[(size_t)(i0w + lgrp*4 + r)*FD + n*16 + lrow] = acc[n][r];
}

// ---------------- K5: combine partials, divide ----------------
__global__ __launch_bounds__(256) void k5_fin(const float* __restrict__ partial,
    const float* __restrict__ denomp, float* __restrict__ out, int njc){
  int g = blockIdx.x*256 + threadIdx.x;
  int i = g >> 7;
  float num = 0.f, den = 0.f;
  for (int c = 0; c < njc; ++c) num += partial[(size_t)c*N*FD + g];
  for (int c = 0; c < njc; ++c) den += denomp[(size_t)c*N + i];
  out[g] = num / den;
}

extern "C" void kernel_launch(void* const* d_in, const int* in_sizes, int n_in,
                              void* d_out, int out_size, void* d_ws, size_t ws_size,
                              hipStream_t stream){
  const float* h   = (const float*)d_in[0];
  const int*   adj = (const int*)d_in[1];
  const float* W   = (const float*)d_in[2];
  const float* a   = (const float*)d_in[3];
  float* out = (float*)d_out;
  char* ws = (char*)d_ws;

  unsigned short* Bsw = (unsigned short*)ws;             // 2 MB
  float* Wh  = (float*)(ws + (size_t)(2u<<20));          // 4 MB
  float* s1L = (float*)(ws + (size_t)(6u<<20));          // 32 KB
  float* s2L = (float*)(ws + (size_t)(6u<<20) + 32768);  // 32 KB
  float* M2L = (float*)(ws + (size_t)(6u<<20) + 65536);  // 4 B
  float* denomp  = (float*)(ws + (size_t)(7u<<20));      // njc*32 KB
  float* partial = (float*)(ws + (size_t)(8u<<20));      // njc*4 MB

  size_t chunk = (size_t)N * FD * sizeof(float);         // 4 MB
  int njc = 1;
  if (ws_size > ((size_t)(8u<<20))){
    size_t m = (ws_size - (size_t)(8u<<20)) / chunk;
    njc = (m >= 8) ? 8 : (m >= 4) ? 4 : (m >= 2) ? 2 : 1;
  }

  hipLaunchKernelGGL(k1_wh,  dim3(256), dim3(256), 0, stream, h, W, Wh, Bsw);
  hipLaunchKernelGGL(k2_s,   dim3(32),  dim3(256), 0, stream, Wh, a, s1L, s2L);
  hipLaunchKernelGGL(k3_max, dim3(1),   dim3(256), 0, stream, s2L, M2L);
  hipLaunchKernelGGL(k4_flash, dim3(128, njc), dim3(256), 0, stream,
                     adj, Bsw, s1L, s2L, M2L, partial, denomp, njc);
  hipLaunchKernelGGL(k5_fin, dim3(N*FD/256), dim3(256), 0, stream, partial, denomp, out, njc);
}

// Round 3
// 486.269 us; speedup vs baseline: 1.0067x; 1.0067x over previous
//
#include <hip/hip_runtime.h>
#include <hip/hip_bf16.h>

#define N 8192
#define FD 128
#define LOG2E 1.4426950408889634f

typedef __attribute__((ext_vector_type(4))) float f4;
typedef __attribute__((ext_vector_type(4))) int i32x4;
typedef __attribute__((ext_vector_type(4))) unsigned int u32x4;
typedef __attribute__((ext_vector_type(8))) __bf16 bf16x8;

__device__ __forceinline__ unsigned short bfbits(float x){
  __bf16 b = (__bf16)x;
  return __builtin_bit_cast(unsigned short, b);
}

// ---- K12: Wh = h @ W (f32) + Bsw (MFMA-B-swizzled bf16) + fused s1L/s2L tail ----
// Bsw flat layout: elem(jblk, n, lane, e) at ((jblk*8+n)*64 + lane)*8 + e
//   holds bf16( Wh[jblk*32 + (lane>>4)*8 + e][n*16 + (lane&15)] )
__global__ __launch_bounds__(256) void k12_wh(const float* __restrict__ h,
                                              const float* __restrict__ W,
                                              const float* __restrict__ a,
                                              unsigned short* __restrict__ Bsw,
                                              float* __restrict__ s1L,
                                              float* __restrict__ s2L){
  __shared__ float Wl[64*128];   // half of W (k-split), 32KB
  __shared__ float hT[128*33];   // h tile transposed [k][r], padded stride 33
  int t = threadIdx.x;
  int i0 = blockIdx.x * 32;
  {
    int r  = t >> 3;           // 0..31
    int k0 = (t & 7) * 16;     // 0,16,...,112
    const f4* src = (const f4*)&h[(size_t)(i0 + r)*FD + k0];
    #pragma unroll
    for (int q = 0; q < 4; ++q){
      f4 v = src[q];
      #pragma unroll
      for (int e = 0; e < 4; ++e) hT[(k0 + q*4 + e)*33 + r] = v[e];
    }
  }
  int f0 = (t & 31) * 4;   // 0..124
  int r0 = (t >> 5) * 4;   // 0..28
  float acc[4][4] = {};
  for (int half = 0; half < 2; ++half){
    __syncthreads();
    #pragma unroll
    for (int v = 0; v < 8; ++v){
      int idx = (v*256 + t)*4;
      *(f4*)&Wl[idx] = *(const f4*)&W[half*8192 + idx];
    }
    __syncthreads();
    for (int k2 = 0; k2 < 64; ++k2){
      f4 wv = *(const f4*)&Wl[k2*FD + f0];
      f4 hv = *(const f4*)&hT[(half*64 + k2)*33 + r0];
      #pragma unroll
      for (int ri = 0; ri < 4; ++ri)
        #pragma unroll
        for (int fi = 0; fi < 4; ++fi)
          acc[ri][fi] = __builtin_fmaf(hv[ri], wv[fi], acc[ri][fi]);
    }
  }
  // Bsw swizzled store
  int jblk = blockIdx.x;
  int n  = f0 >> 4;
  int fl = f0 & 15;
  #pragma unroll
  for (int ri = 0; ri < 4; ++ri){
    int k = r0 + ri;
    size_t base = (((size_t)jblk*8 + n)*64 + ((k>>3)<<4))*8 + (k&7);
    #pragma unroll
    for (int fi = 0; fi < 4; ++fi)
      Bsw[base + (size_t)(fl + fi)*8] = bfbits(acc[ri][fi]);
  }
  // fused s1/s2 tail: per-thread partial dot over its 4 features, 4 rows
  f4 a1v = *(const f4*)&a[f0];
  f4 a2v = *(const f4*)&a[FD + f0];
  float p1[4], p2[4];
  #pragma unroll
  for (int ri = 0; ri < 4; ++ri){
    p1[ri] = 0.f; p2[ri] = 0.f;
    #pragma unroll
    for (int fi = 0; fi < 4; ++fi){
      p1[ri] = __builtin_fmaf(acc[ri][fi], a1v[fi], p1[ri]);
      p2[ri] = __builtin_fmaf(acc[ri][fi], a2v[fi], p2[ri]);
    }
  }
  #pragma unroll
  for (int d = 1; d < 32; d <<= 1){
    #pragma unroll
    for (int ri = 0; ri < 4; ++ri){
      p1[ri] += __shfl_xor(p1[ri], d, 32);
      p2[ri] += __shfl_xor(p2[ri], d, 32);
    }
  }
  if ((t & 31) == 0){
    #pragma unroll
    for (int ri = 0; ri < 4; ++ri){
      s1L[i0 + r0 + ri] = p1[ri] * LOG2E;
      s2L[i0 + r0 + ri] = p2[ri] * LOG2E;
    }
  }
}

// ---------------- K3: M2L = max(s2L) ----------------
__global__ __launch_bounds__(256) void k3_max(const float* __restrict__ s2L,
                                              float* __restrict__ M2L){
  __shared__ float red[4];
  int t = threadIdx.x;
  float m = -3.0e38f;
  for (int i = t; i < N; i += 256) m = fmaxf(m, s2L[i]);
  #pragma unroll
  for (int d = 1; d < 64; d <<= 1) m = fmaxf(m, __shfl_xor(m, d, 64));
  if ((t & 63) == 0) red[t >> 6] = m;
  __syncthreads();
  if (t == 0) *M2L = fmaxf(fmaxf(red[0], red[1]), fmaxf(red[2], red[3]));
}

// ---------------- K4: fused masked-softmax numerator + denominator ----------------
// Wave owns 16 rows x j-chunk. adj is read COALESCED (lane = 8 consecutive ints of
// one row), compressed to 1 bit/entry in registers, parked in wave-private LDS
// (512B per macro-tile of 256 j). No barriers. Compute phase: 1 mask byte per
// iter from LDS + coalesced Bsw B-frags + 9 MFMA. adj read exactly once.
__global__ __launch_bounds__(256,2) void k4_flash(const int* __restrict__ adj,
    const unsigned short* __restrict__ Bsw,
    const float* __restrict__ s1L, const float* __restrict__ s2L,
    const float* __restrict__ M2p,
    float* __restrict__ partial, float* __restrict__ denomp, int njc){
  __shared__ unsigned char mk[4][2][16][32];   // [wave][buf][row][byte] = 4KB
  int t = threadIdx.x;
  int wv = t >> 6, lane = t & 63;
  int lrow = lane & 15, lgrp = lane >> 4;
  int i0w = blockIdx.x * 64 + wv * 16;         // wave's 16 rows
  int jlen = N / njc;
  int jstart = blockIdx.y * jlen;
  int nmac = jlen >> 8;                        // macro-tiles of 256 j
  float M2 = *M2p;
  float s1a = s1L[i0w + lrow];
  float ea = s1a + M2;
  float maL = fmaxf(ea, 0.2f*ea);              // row-max upper bound (log2-space)

  f4 acc[8];
  #pragma unroll
  for (int n = 0; n < 8; ++n) acc[n] = (f4){0.f,0.f,0.f,0.f};
  f4 accd = (f4){0.f,0.f,0.f,0.f};
  u32x4 onesbits = (u32x4){0x3F803F80u,0x3F803F80u,0x3F803F80u,0x3F803F80u};
  bf16x8 ones = __builtin_bit_cast(bf16x8, onesbits);

  const i32x4* adj4 = (const i32x4*)adj;
  const f4* s2v = (const f4*)s2L;
  // staging address base: lane covers row i0w + 2p + (lane>>5), ints (lane&31)*8 ..+8
  size_t stbase = (((size_t)(i0w + (lane >> 5)) * N) + (size_t)(lane & 31) * 8) >> 2; // i32x4 units
  const size_t rowstep2 = ((size_t)2 * N) >> 2;   // 2 rows in i32x4 units

  i32x4 st[16];
  // prologue: stage macro 0 into buf 0
  {
    size_t b0 = stbase + ((size_t)jstart >> 2);
    #pragma unroll
    for (int p = 0; p < 8; ++p){
      st[2*p]   = adj4[b0 + (size_t)p * rowstep2];
      st[2*p+1] = adj4[b0 + (size_t)p * rowstep2 + 1];
    }
    #pragma unroll
    for (int p = 0; p < 8; ++p){
      unsigned v = 0;
      #pragma unroll
      for (int e = 0; e < 4; ++e){
        v |= (st[2*p][e]   != 0) ? (1u << e)     : 0u;
        v |= (st[2*p+1][e] != 0) ? (1u << (4+e)) : 0u;
      }
      mk[wv][0][2*p + (lane >> 5)][lane & 31] = (unsigned char)v;
    }
  }

  for (int m = 0; m < nmac; ++m){
    int bf = m & 1;
    int jbase = jstart + m*256;
    // issue next macro's adj loads (coalesced, deep prefetch)
    if (m + 1 < nmac){
      size_t bn = stbase + ((size_t)(jbase + 256) >> 2);
      #pragma unroll
      for (int p = 0; p < 8; ++p){
        st[2*p]   = adj4[bn + (size_t)p * rowstep2];
        st[2*p+1] = adj4[bn + (size_t)p * rowstep2 + 1];
      }
    }
    // compute 8 j-tiles of 32 from buf bf
    int jt0 = jbase >> 5;
    #pragma unroll
    for (int js = 0; js < 8; ++js){
      int jb = jbase + js*32 + lgrp*8;
      unsigned mbyte = mk[wv][bf][lrow][js*4 + lgrp];
      f4 ya = s2v[jb >> 2], yb = s2v[(jb >> 2) + 1];
      u32x4 braw[8];
      #pragma unroll
      for (int n = 0; n < 8; ++n)
        braw[n] = *(const u32x4*)&Bsw[((((size_t)(jt0 + js)*8 + n)*64) + lane)*8];
      bf16x8 fa;
      #pragma unroll
      for (int e = 0; e < 8; ++e){
        float sj = (e < 4) ? ya[e] : yb[e-4];
        float x  = s1a + sj;
        float lr = fmaxf(x, 0.2f*x);
        float p  = ((mbyte >> e) & 1u) ? __builtin_amdgcn_exp2f(lr - maL) : 0.f;
        fa[e] = (__bf16)p;
      }
      accd = __builtin_amdgcn_mfma_f32_16x16x32_bf16(fa, ones, accd, 0, 0, 0);
      #pragma unroll
      for (int n = 0; n < 8; ++n)
        acc[n] = __builtin_amdgcn_mfma_f32_16x16x32_bf16(fa,
                   __builtin_bit_cast(bf16x8, braw[n]), acc[n], 0, 0, 0);
    }
    // park next macro's mask bytes
    if (m + 1 < nmac){
      #pragma unroll
      for (int p = 0; p < 8; ++p){
        unsigned v = 0;
        #pragma unroll
        for (int e = 0; e < 4; ++e){
          v |= (st[2*p][e]   != 0) ? (1u << e)     : 0u;
          v |= (st[2*p+1][e] != 0) ? (1u << (4+e)) : 0u;
        }
        mk[wv][bf ^ 1][2*p + (lane >> 5)][lane & 31] = (unsigned char)v;
      }
    }
  }

  if (lrow == 0){
    #pragma unroll
    for (int r = 0; r < 4; ++r)
      denomp[(size_t)blockIdx.y*N + i0w + lgrp*4 + r] = accd[r];
  }
  float* pb = partial + (size_t)blockIdx.y * N * FD;
  #pragma unroll
  for (int n = 0; n < 8; ++n)
    #pragma unroll
    for (int r = 0; r < 4; ++r)
      pb[(size_t)(i0w + lgrp*4 + r)*FD + n*16 + lrow] = acc[n][r];
}

// ---------------- K5: combine partials, divide ----------------
__global__ __launch_bounds__(256) void k5_fin(const float* __restrict__ partial,
    const float* __restrict__ denomp, float* __restrict__ out, int njc){
  int g = blockIdx.x*256 + threadIdx.x;
  int i = g >> 7;
  float num = 0.f, den = 0.f;
  for (int c = 0; c < njc; ++c) num += partial[(size_t)c*N*FD + g];
  for (int c = 0; c < njc; ++c) den += denomp[(size_t)c*N + i];
  out[g] = num / den;
}

extern "C" void kernel_launch(void* const* d_in, const int* in_sizes, int n_in,
                              void* d_out, int out_size, void* d_ws, size_t ws_size,
                              hipStream_t stream){
  const float* h   = (const float*)d_in[0];
  const int*   adj = (const int*)d_in[1];
  const float* W   = (const float*)d_in[2];
  const float* a   = (const float*)d_in[3];
  float* out = (float*)d_out;
  char* ws = (char*)d_ws;

  unsigned short* Bsw = (unsigned short*)ws;             // 2 MB
  float* s1L = (float*)(ws + (size_t)(6u<<20));          // 32 KB
  float* s2L = (float*)(ws + (size_t)(6u<<20) + 32768);  // 32 KB
  float* M2L = (float*)(ws + (size_t)(6u<<20) + 65536);  // 4 B
  float* denomp  = (float*)(ws + (size_t)(7u<<20));      // njc*32 KB
  float* partial = (float*)(ws + (size_t)(8u<<20));      // njc*4 MB

  size_t chunk = (size_t)N * FD * sizeof(float);         // 4 MB
  int njc = 1;
  if (ws_size > ((size_t)(8u<<20))){
    size_t m = (ws_size - (size_t)(8u<<20)) / chunk;
    njc = (m >= 8) ? 8 : (m >= 4) ? 4 : (m >= 2) ? 2 : 1;
  }

  hipLaunchKernelGGL(k12_wh, dim3(256), dim3(256), 0, stream, h, W, a, Bsw, s1L, s2L);
  hipLaunchKernelGGL(k3_max, dim3(1),   dim3(256), 0, stream, s2L, M2L);
  hipLaunchKernelGGL(k4_flash, dim3(128, njc), dim3(256), 0, stream,
                     adj, Bsw, s1L, s2L, M2L, partial, denomp, njc);
  hipLaunchKernelGGL(k5_fin, dim3(N*FD/256), dim3(256), 0, stream, partial, denomp, out, njc);
}

// Round 4
// 448.181 us; speedup vs baseline: 1.0923x; 1.0850x over previous
//
#include <hip/hip_runtime.h>
#include <hip/hip_bf16.h>

#define N 8192
#define FD 128
#define LOG2E 1.4426950408889634f

typedef __attribute__((ext_vector_type(4))) float f4;
typedef __attribute__((ext_vector_type(4))) int i32x4;
typedef __attribute__((ext_vector_type(4))) unsigned int u32x4;
typedef __attribute__((ext_vector_type(8))) __bf16 bf16x8;

__device__ __forceinline__ unsigned short bfbits(float x){
  __bf16 b = (__bf16)x;
  return __builtin_bit_cast(unsigned short, b);
}

// ---- K12: Wh = h @ W (f32) + Bsw (MFMA-B-swizzled bf16) + fused s1L/s2L tail ----
// Bsw flat layout: elem(jblk, n, lane, e) at ((jblk*8+n)*64 + lane)*8 + e
//   holds bf16( Wh[jblk*32 + (lane>>4)*8 + e][n*16 + (lane&15)] )
__global__ __launch_bounds__(256) void k12_wh(const float* __restrict__ h,
                                              const float* __restrict__ W,
                                              const float* __restrict__ a,
                                              unsigned short* __restrict__ Bsw,
                                              float* __restrict__ s1L,
                                              float* __restrict__ s2L){
  __shared__ float Wl[64*128];
  __shared__ float hT[128*33];
  int t = threadIdx.x;
  int i0 = blockIdx.x * 32;
  {
    int r  = t >> 3;
    int k0 = (t & 7) * 16;
    const f4* src = (const f4*)&h[(size_t)(i0 + r)*FD + k0];
    #pragma unroll
    for (int q = 0; q < 4; ++q){
      f4 v = src[q];
      #pragma unroll
      for (int e = 0; e < 4; ++e) hT[(k0 + q*4 + e)*33 + r] = v[e];
    }
  }
  int f0 = (t & 31) * 4;
  int r0 = (t >> 5) * 4;
  float acc[4][4] = {};
  for (int half = 0; half < 2; ++half){
    __syncthreads();
    #pragma unroll
    for (int v = 0; v < 8; ++v){
      int idx = (v*256 + t)*4;
      *(f4*)&Wl[idx] = *(const f4*)&W[half*8192 + idx];
    }
    __syncthreads();
    for (int k2 = 0; k2 < 64; ++k2){
      f4 wv = *(const f4*)&Wl[k2*FD + f0];
      f4 hv = *(const f4*)&hT[(half*64 + k2)*33 + r0];
      #pragma unroll
      for (int ri = 0; ri < 4; ++ri)
        #pragma unroll
        for (int fi = 0; fi < 4; ++fi)
          acc[ri][fi] = __builtin_fmaf(hv[ri], wv[fi], acc[ri][fi]);
    }
  }
  int jblk = blockIdx.x;
  int n  = f0 >> 4;
  int fl = f0 & 15;
  #pragma unroll
  for (int ri = 0; ri < 4; ++ri){
    int k = r0 + ri;
    size_t base = (((size_t)jblk*8 + n)*64 + ((k>>3)<<4))*8 + (k&7);
    #pragma unroll
    for (int fi = 0; fi < 4; ++fi)
      Bsw[base + (size_t)(fl + fi)*8] = bfbits(acc[ri][fi]);
  }
  f4 a1v = *(const f4*)&a[f0];
  f4 a2v = *(const f4*)&a[FD + f0];
  float p1[4], p2[4];
  #pragma unroll
  for (int ri = 0; ri < 4; ++ri){
    p1[ri] = 0.f; p2[ri] = 0.f;
    #pragma unroll
    for (int fi = 0; fi < 4; ++fi){
      p1[ri] = __builtin_fmaf(acc[ri][fi], a1v[fi], p1[ri]);
      p2[ri] = __builtin_fmaf(acc[ri][fi], a2v[fi], p2[ri]);
    }
  }
  #pragma unroll
  for (int d = 1; d < 32; d <<= 1){
    #pragma unroll
    for (int ri = 0; ri < 4; ++ri){
      p1[ri] += __shfl_xor(p1[ri], d, 32);
      p2[ri] += __shfl_xor(p2[ri], d, 32);
    }
  }
  if ((t & 31) == 0){
    #pragma unroll
    for (int ri = 0; ri < 4; ++ri){
      s1L[i0 + r0 + ri] = p1[ri] * LOG2E;
      s2L[i0 + r0 + ri] = p2[ri] * LOG2E;
    }
  }
}

// ---------------- K3: M2L = max(s2L) ----------------
__global__ __launch_bounds__(256) void k3_max(const float* __restrict__ s2L,
                                              float* __restrict__ M2L){
  __shared__ float red[4];
  int t = threadIdx.x;
  float m = -3.0e38f;
  for (int i = t; i < N; i += 256) m = fmaxf(m, s2L[i]);
  #pragma unroll
  for (int d = 1; d < 64; d <<= 1) m = fmaxf(m, __shfl_xor(m, d, 64));
  if ((t & 63) == 0) red[t >> 6] = m;
  __syncthreads();
  if (t == 0) *M2L = fmaxf(fmaxf(red[0], red[1]), fmaxf(red[2], red[3]));
}

// ---------------- K4 v3: LDS-staged macro GEMM ----------------
// Block = 256 thr (4 waves x 32 rows) owns 128 rows x one j-chunk.
// Per 128-j macro: stage Bsw slice (32KB, read ONCE per block), adj as 1-bit
// masks (2KB), s2 slice (512B) -> barrier -> 4 js-tiles x 18 MFMA from LDS.
// Cuts Bsw global traffic 1GB -> 128MB; fragment reads now LDS-speed.
__global__ __launch_bounds__(256,2) void k4_flash(const int* __restrict__ adj,
    const unsigned short* __restrict__ Bsw,
    const float* __restrict__ s1L, const float* __restrict__ s2L,
    const float* __restrict__ M2p,
    float* __restrict__ partial, float* __restrict__ denomp, int njc){
  __shared__ unsigned char bswl[32768];          // Bsw macro slice
  __shared__ unsigned long long mkl[128][2];     // masks [row][64j-half]
  __shared__ float s2l[128];
  int t = threadIdx.x;
  int wv = t >> 6, lane = t & 63;
  int lrow = lane & 15, lgrp = lane >> 4;
  int bx = blockIdx.x;
  int jlen = N / njc;
  int jstart = blockIdx.y * jlen;
  int nmac = jlen >> 7;
  float M2 = *M2p;
  int i0w = bx*128 + wv*32;
  float s1a = s1L[i0w + lrow], s1b = s1L[i0w + 16 + lrow];
  float ea = s1a + M2, eb = s1b + M2;
  float maL = fmaxf(ea, 0.2f*ea);
  float mbL = fmaxf(eb, 0.2f*eb);

  f4 acc[2][8]; f4 accd[2];
  #pragma unroll
  for (int x = 0; x < 2; ++x){
    accd[x] = (f4){0.f,0.f,0.f,0.f};
    #pragma unroll
    for (int n = 0; n < 8; ++n) acc[x][n] = (f4){0.f,0.f,0.f,0.f};
  }
  u32x4 onesbits = (u32x4){0x3F803F80u,0x3F803F80u,0x3F803F80u,0x3F803F80u};
  bf16x8 ones = __builtin_bit_cast(bf16x8, onesbits);

  int srow = t >> 1;            // staging: local row 0..127
  int shalf = t & 1;            // which 64-j half
  const i32x4* adjrow = (const i32x4*)(adj + (size_t)(bx*128 + srow)*N);

  for (int m = 0; m < nmac; ++m){
    int jb0 = jstart + m*128;
    // ---- stage adj -> 1-bit masks ----
    i32x4 st[16];
    int ib = (jb0 + shalf*64) >> 2;
    #pragma unroll
    for (int e = 0; e < 16; ++e) st[e] = adjrow[ib + e];
    // ---- stage Bsw slice (coalesced, contiguous 32KB) ----
    {
      const u32x4* src = (const u32x4*)(Bsw + (size_t)(jb0 >> 5) * 4096);
      u32x4* dst = (u32x4*)bswl;
      #pragma unroll
      for (int q = 0; q < 8; ++q)
        dst[q*256 + t] = src[q*256 + t];
    }
    if (t < 128) s2l[t] = s2L[jb0 + t];
    unsigned long long mv = 0ull;
    #pragma unroll
    for (int e = 0; e < 16; ++e){
      #pragma unroll
      for (int c = 0; c < 4; ++c)
        mv |= (st[e][c] != 0) ? (1ull << (e*4 + c)) : 0ull;
    }
    mkl[srow][shalf] = mv;
    __syncthreads();
    // ---- compute 4 js-tiles from LDS ----
    const unsigned char* mkb = (const unsigned char*)mkl;
    #pragma unroll
    for (int js = 0; js < 4; ++js){
      int jo = js*32 + lgrp*8;
      f4 ya = *(const f4*)&s2l[jo];
      f4 yb = *(const f4*)&s2l[jo+4];
      unsigned mba = mkb[(wv*32 + lrow)*16 + js*4 + lgrp];
      unsigned mbb = mkb[(wv*32 + 16 + lrow)*16 + js*4 + lgrp];
      u32x4 braw[8];
      #pragma unroll
      for (int n = 0; n < 8; ++n)
        braw[n] = *(const u32x4*)&bswl[((js*8 + n)*64 + lane)*16];
      bf16x8 fa, fb;
      #pragma unroll
      for (int e = 0; e < 8; ++e){
        float sj = (e < 4) ? ya[e] : yb[e-4];
        float xa = s1a + sj,               xb = s1b + sj;
        float la = fmaxf(xa, 0.2f*xa),     lb = fmaxf(xb, 0.2f*xb);
        float pa = ((mba>>e)&1u) ? __builtin_amdgcn_exp2f(la - maL) : 0.f;
        float pb = ((mbb>>e)&1u) ? __builtin_amdgcn_exp2f(lb - mbL) : 0.f;
        fa[e] = (__bf16)pa; fb[e] = (__bf16)pb;
      }
      accd[0] = __builtin_amdgcn_mfma_f32_16x16x32_bf16(fa, ones, accd[0], 0, 0, 0);
      accd[1] = __builtin_amdgcn_mfma_f32_16x16x32_bf16(fb, ones, accd[1], 0, 0, 0);
      #pragma unroll
      for (int n = 0; n < 8; ++n){
        bf16x8 bb = __builtin_bit_cast(bf16x8, braw[n]);
        acc[0][n] = __builtin_amdgcn_mfma_f32_16x16x32_bf16(fa, bb, acc[0][n], 0, 0, 0);
        acc[1][n] = __builtin_amdgcn_mfma_f32_16x16x32_bf16(fb, bb, acc[1][n], 0, 0, 0);
      }
    }
    __syncthreads();
  }

  if (lrow == 0){
    #pragma unroll
    for (int x = 0; x < 2; ++x)
      #pragma unroll
      for (int r = 0; r < 4; ++r)
        denomp[(size_t)blockIdx.y*N + i0w + x*16 + lgrp*4 + r] = accd[x][r];
  }
  float* pb = partial + (size_t)blockIdx.y * N * FD;
  #pragma unroll
  for (int x = 0; x < 2; ++x)
    #pragma unroll
    for (int n = 0; n < 8; ++n)
      #pragma unroll
      for (int r = 0; r < 4; ++r)
        pb[(size_t)(i0w + x*16 + lgrp*4 + r)*FD + n*16 + lrow] = acc[x][n][r];
}

// ---------------- K5: combine partials, divide ----------------
__global__ __launch_bounds__(256) void k5_fin(const float* __restrict__ partial,
    const float* __restrict__ denomp, float* __restrict__ out, int njc){
  int g = blockIdx.x*256 + threadIdx.x;
  int i = g >> 7;
  float num = 0.f, den = 0.f;
  for (int c = 0; c < njc; ++c) num += partial[(size_t)c*N*FD + g];
  for (int c = 0; c < njc; ++c) den += denomp[(size_t)c*N + i];
  out[g] = num / den;
}

extern "C" void kernel_launch(void* const* d_in, const int* in_sizes, int n_in,
                              void* d_out, int out_size, void* d_ws, size_t ws_size,
                              hipStream_t stream){
  const float* h   = (const float*)d_in[0];
  const int*   adj = (const int*)d_in[1];
  const float* W   = (const float*)d_in[2];
  const float* a   = (const float*)d_in[3];
  float* out = (float*)d_out;
  char* ws = (char*)d_ws;

  unsigned short* Bsw = (unsigned short*)ws;             // 2 MB
  float* s1L = (float*)(ws + (size_t)(6u<<20));          // 32 KB
  float* s2L = (float*)(ws + (size_t)(6u<<20) + 32768);  // 32 KB
  float* M2L = (float*)(ws + (size_t)(6u<<20) + 65536);  // 4 B
  float* denomp  = (float*)(ws + (size_t)(7u<<20));      // njc*32 KB
  float* partial = (float*)(ws + (size_t)(8u<<20));      // njc*4 MB

  size_t chunk = (size_t)N * FD * sizeof(float);         // 4 MB
  int njc = 1;
  if (ws_size > ((size_t)(8u<<20))){
    size_t m = (ws_size - (size_t)(8u<<20)) / chunk;
    njc = (m >= 8) ? 8 : (m >= 4) ? 4 : (m >= 2) ? 2 : 1;
  }

  hipLaunchKernelGGL(k12_wh, dim3(256), dim3(256), 0, stream, h, W, a, Bsw, s1L, s2L);
  hipLaunchKernelGGL(k3_max, dim3(1),   dim3(256), 0, stream, s2L, M2L);
  hipLaunchKernelGGL(k4_flash, dim3(64, njc), dim3(256), 0, stream,
                     adj, Bsw, s1L, s2L, M2L, partial, denomp, njc);
  hipLaunchKernelGGL(k5_fin, dim3(N*FD/256), dim3(256), 0, stream, partial, denomp, out, njc);
}

// Round 5
// 436.970 us; speedup vs baseline: 1.1203x; 1.0257x over previous
//
#include <hip/hip_runtime.h>
#include <hip/hip_bf16.h>

#define N 8192
#define FD 128
#define LOG2E 1.4426950408889634f

typedef __attribute__((ext_vector_type(4))) float f4;
typedef __attribute__((ext_vector_type(4))) int i32x4;
typedef __attribute__((ext_vector_type(4))) unsigned int u32x4;
typedef __attribute__((ext_vector_type(8))) __bf16 bf16x8;

__device__ __forceinline__ unsigned short bfbits(float x){
  __bf16 b = (__bf16)x;
  return __builtin_bit_cast(unsigned short, b);
}

// ---- K12: Wh = h @ W (f32) + Bsw (MFMA-B-swizzled bf16) + fused s1L/s2L tail ----
// Bsw flat layout: elem(jblk, n, lane, e) at ((jblk*8+n)*64 + lane)*8 + e
//   holds bf16( Wh[jblk*32 + (lane>>4)*8 + e][n*16 + (lane&15)] )
__global__ __launch_bounds__(256) void k12_wh(const float* __restrict__ h,
                                              const float* __restrict__ W,
                                              const float* __restrict__ a,
                                              unsigned short* __restrict__ Bsw,
                                              float* __restrict__ s1L,
                                              float* __restrict__ s2L){
  __shared__ float Wl[64*128];
  __shared__ float hT[128*33];
  int t = threadIdx.x;
  int i0 = blockIdx.x * 32;
  {
    int r  = t >> 3;
    int k0 = (t & 7) * 16;
    const f4* src = (const f4*)&h[(size_t)(i0 + r)*FD + k0];
    #pragma unroll
    for (int q = 0; q < 4; ++q){
      f4 v = src[q];
      #pragma unroll
      for (int e = 0; e < 4; ++e) hT[(k0 + q*4 + e)*33 + r] = v[e];
    }
  }
  int f0 = (t & 31) * 4;
  int r0 = (t >> 5) * 4;
  float acc[4][4] = {};
  for (int half = 0; half < 2; ++half){
    __syncthreads();
    #pragma unroll
    for (int v = 0; v < 8; ++v){
      int idx = (v*256 + t)*4;
      *(f4*)&Wl[idx] = *(const f4*)&W[half*8192 + idx];
    }
    __syncthreads();
    for (int k2 = 0; k2 < 64; ++k2){
      f4 wv = *(const f4*)&Wl[k2*FD + f0];
      f4 hv = *(const f4*)&hT[(half*64 + k2)*33 + r0];
      #pragma unroll
      for (int ri = 0; ri < 4; ++ri)
        #pragma unroll
        for (int fi = 0; fi < 4; ++fi)
          acc[ri][fi] = __builtin_fmaf(hv[ri], wv[fi], acc[ri][fi]);
    }
  }
  int jblk = blockIdx.x;
  int n  = f0 >> 4;
  int fl = f0 & 15;
  #pragma unroll
  for (int ri = 0; ri < 4; ++ri){
    int k = r0 + ri;
    size_t base = (((size_t)jblk*8 + n)*64 + ((k>>3)<<4))*8 + (k&7);
    #pragma unroll
    for (int fi = 0; fi < 4; ++fi)
      Bsw[base + (size_t)(fl + fi)*8] = bfbits(acc[ri][fi]);
  }
  f4 a1v = *(const f4*)&a[f0];
  f4 a2v = *(const f4*)&a[FD + f0];
  float p1[4], p2[4];
  #pragma unroll
  for (int ri = 0; ri < 4; ++ri){
    p1[ri] = 0.f; p2[ri] = 0.f;
    #pragma unroll
    for (int fi = 0; fi < 4; ++fi){
      p1[ri] = __builtin_fmaf(acc[ri][fi], a1v[fi], p1[ri]);
      p2[ri] = __builtin_fmaf(acc[ri][fi], a2v[fi], p2[ri]);
    }
  }
  #pragma unroll
  for (int d = 1; d < 32; d <<= 1){
    #pragma unroll
    for (int ri = 0; ri < 4; ++ri){
      p1[ri] += __shfl_xor(p1[ri], d, 32);
      p2[ri] += __shfl_xor(p2[ri], d, 32);
    }
  }
  if ((t & 31) == 0){
    #pragma unroll
    for (int ri = 0; ri < 4; ++ri){
      s1L[i0 + r0 + ri] = p1[ri] * LOG2E;
      s2L[i0 + r0 + ri] = p2[ri] * LOG2E;
    }
  }
}

// ---------------- K3: M2L = max(s2L) ----------------
__global__ __launch_bounds__(256) void k3_max(const float* __restrict__ s2L,
                                              float* __restrict__ M2L){
  __shared__ float red[4];
  int t = threadIdx.x;
  float m = -3.0e38f;
  for (int i = t; i < N; i += 256) m = fmaxf(m, s2L[i]);
  #pragma unroll
  for (int d = 1; d < 64; d <<= 1) m = fmaxf(m, __shfl_xor(m, d, 64));
  if ((t & 63) == 0) red[t >> 6] = m;
  __syncthreads();
  if (t == 0) *M2L = fmaxf(fmaxf(red[0], red[1]), fmaxf(red[2], red[3]));
}

// ---------------- K4 v4: coalesced-adj + async-Bsw LDS macro GEMM ----------------
// Block = 256 thr (4 waves), 128 rows x one j-chunk, 4 blocks/CU.
// Per 128-j macro: (a) async Bsw slice -> LDS via global_load_lds (linear both
// sides), (b) adj read with TRUE lane-coalescing (lane = (row-parity, 4 ints)),
// packed to nibbles in LDS, (c) barrier, (d) 4 js-tiles x 18 MFMA from LDS.
__global__ __launch_bounds__(256,4) void k4_flash(const int* __restrict__ adj,
    const unsigned short* __restrict__ Bsw,
    const float* __restrict__ s1L, const float* __restrict__ s2L,
    const float* __restrict__ M2p,
    float* __restrict__ partial, float* __restrict__ denomp, int njc){
  __shared__ __align__(16) unsigned char bswl[32768];   // Bsw macro slice
  __shared__ __align__(16) unsigned char mknib[128*32]; // nibble masks [row][32]
  __shared__ __align__(16) float s2l[128];
  int t = threadIdx.x;
  int wv = t >> 6, lane = t & 63;
  int lrow = lane & 15, lgrp = lane >> 4;
  int bx = blockIdx.x;
  int jlen = N / njc;
  int jstart = blockIdx.y * jlen;
  int nmac = jlen >> 7;
  float M2 = *M2p;
  int i0w = bx*128 + wv*32;
  float s1a = s1L[i0w + lrow], s1b = s1L[i0w + 16 + lrow];
  float ea = s1a + M2, eb = s1b + M2;
  float maL = fmaxf(ea, 0.2f*ea);
  float mbL = fmaxf(eb, 0.2f*eb);

  f4 acc[2][8]; f4 accd[2];
  #pragma unroll
  for (int x = 0; x < 2; ++x){
    accd[x] = (f4){0.f,0.f,0.f,0.f};
    #pragma unroll
    for (int n = 0; n < 8; ++n) acc[x][n] = (f4){0.f,0.f,0.f,0.f};
  }
  u32x4 onesbits = (u32x4){0x3F803F80u,0x3F803F80u,0x3F803F80u,0x3F803F80u};
  bf16x8 ones = __builtin_bit_cast(bf16x8, onesbits);

  const i32x4* adj4 = (const i32x4*)adj;
  // staging: lane covers (row = wv*32 + e*2 + (lane>>5), ints (lane&31)*4..+4)
  int sr2 = lane >> 5;                 // row parity
  int sj  = lane & 31;                 // 4-int group within 128-j macro
  size_t abase = ((size_t)(bx*128 + wv*32 + sr2) * N) >> 2;   // i32x4 units

  for (int m = 0; m < nmac; ++m){
    int jb0 = jstart + m*128;
    // ---- (a) async Bsw slice -> LDS (32KB, 32 chunk-loads of 1KB) ----
    const unsigned int* bg = (const unsigned int*)(Bsw + (size_t)(jb0 >> 5) * 4096);
    #pragma unroll
    for (int q = 0; q < 8; ++q){
      int chunk = q*4 + wv;
      __builtin_amdgcn_global_load_lds(
        (const __attribute__((address_space(1))) unsigned int*)(bg + (size_t)(chunk*64 + lane)*4),
        (__attribute__((address_space(3))) unsigned int*)(bswl + chunk*1024),
        16, 0, 0);
    }
    // ---- (b) adj coalesced loads -> nibble masks (4 batches of 4 rows-pairs) ----
    size_t ab = abase + (size_t)(jb0 >> 2) + sj;
    #pragma unroll
    for (int eb = 0; eb < 4; ++eb){
      i32x4 st[4];
      #pragma unroll
      for (int e = 0; e < 4; ++e)
        st[e] = adj4[ab + (size_t)(eb*4 + e) * 4096];
      #pragma unroll
      for (int e = 0; e < 4; ++e){
        unsigned nib = (st[e][0] != 0 ? 1u : 0u) | (st[e][1] != 0 ? 2u : 0u)
                     | (st[e][2] != 0 ? 4u : 0u) | (st[e][3] != 0 ? 8u : 0u);
        int rloc = wv*32 + (eb*4 + e)*2 + sr2;
        mknib[rloc*32 + sj] = (unsigned char)nib;
      }
    }
    if (t < 32) *(f4*)&s2l[t*4] = *(const f4*)&s2L[jb0 + t*4];
    __syncthreads();
    // ---- (d) compute 4 js-tiles from LDS ----
    #pragma unroll
    for (int js = 0; js < 4; ++js){
      int jo = js*32 + lgrp*8;
      f4 ya = *(const f4*)&s2l[jo];
      f4 yb = *(const f4*)&s2l[jo+4];
      int gb = (js*4 + lgrp)*2;
      unsigned short ua = *(const unsigned short*)&mknib[(wv*32 + lrow)*32 + gb];
      unsigned short ub = *(const unsigned short*)&mknib[(wv*32 + 16 + lrow)*32 + gb];
      unsigned mba = (ua & 0xFu) | ((ua >> 4) & 0xF0u);
      unsigned mbb = (ub & 0xFu) | ((ub >> 4) & 0xF0u);
      bf16x8 fa, fb;
      #pragma unroll
      for (int e = 0; e < 8; ++e){
        float sjv = (e < 4) ? ya[e] : yb[e-4];
        float xa = s1a + sjv,            xb = s1b + sjv;
        float la = fmaxf(xa, 0.2f*xa),   lb = fmaxf(xb, 0.2f*xb);
        float pa = ((mba>>e)&1u) ? __builtin_amdgcn_exp2f(la - maL) : 0.f;
        float pb = ((mbb>>e)&1u) ? __builtin_amdgcn_exp2f(lb - mbL) : 0.f;
        fa[e] = (__bf16)pa; fb[e] = (__bf16)pb;
      }
      accd[0] = __builtin_amdgcn_mfma_f32_16x16x32_bf16(fa, ones, accd[0], 0, 0, 0);
      accd[1] = __builtin_amdgcn_mfma_f32_16x16x32_bf16(fb, ones, accd[1], 0, 0, 0);
      // split 4+4 to bound live B-frag registers
      {
        u32x4 b0[4];
        #pragma unroll
        for (int n = 0; n < 4; ++n)
          b0[n] = *(const u32x4*)&bswl[((js*8 + n)*64 + lane)*16];
        #pragma unroll
        for (int n = 0; n < 4; ++n){
          bf16x8 bb = __builtin_bit_cast(bf16x8, b0[n]);
          acc[0][n] = __builtin_amdgcn_mfma_f32_16x16x32_bf16(fa, bb, acc[0][n], 0, 0, 0);
          acc[1][n] = __builtin_amdgcn_mfma_f32_16x16x32_bf16(fb, bb, acc[1][n], 0, 0, 0);
        }
      }
      {
        u32x4 b1[4];
        #pragma unroll
        for (int n = 0; n < 4; ++n)
          b1[n] = *(const u32x4*)&bswl[((js*8 + 4 + n)*64 + lane)*16];
        #pragma unroll
        for (int n = 0; n < 4; ++n){
          bf16x8 bb = __builtin_bit_cast(bf16x8, b1[n]);
          acc[0][4+n] = __builtin_amdgcn_mfma_f32_16x16x32_bf16(fa, bb, acc[0][4+n], 0, 0, 0);
          acc[1][4+n] = __builtin_amdgcn_mfma_f32_16x16x32_bf16(fb, bb, acc[1][4+n], 0, 0, 0);
        }
      }
    }
    __syncthreads();
  }

  if (lrow == 0){
    #pragma unroll
    for (int x = 0; x < 2; ++x)
      #pragma unroll
      for (int r = 0; r < 4; ++r)
        denomp[(size_t)blockIdx.y*N + i0w + x*16 + lgrp*4 + r] = accd[x][r];
  }
  float* pb = partial + (size_t)blockIdx.y * N * FD;
  #pragma unroll
  for (int x = 0; x < 2; ++x)
    #pragma unroll
    for (int n = 0; n < 8; ++n)
      #pragma unroll
      for (int r = 0; r < 4; ++r)
        pb[(size_t)(i0w + x*16 + lgrp*4 + r)*FD + n*16 + lrow] = acc[x][n][r];
}

// ---------------- K5: combine partials, divide ----------------
__global__ __launch_bounds__(256) void k5_fin(const float* __restrict__ partial,
    const float* __restrict__ denomp, float* __restrict__ out, int njc){
  int g = blockIdx.x*256 + threadIdx.x;
  int i = g >> 7;
  float num = 0.f, den = 0.f;
  for (int c = 0; c < njc; ++c) num += partial[(size_t)c*N*FD + g];
  for (int c = 0; c < njc; ++c) den += denomp[(size_t)c*N + i];
  out[g] = num / den;
}

extern "C" void kernel_launch(void* const* d_in, const int* in_sizes, int n_in,
                              void* d_out, int out_size, void* d_ws, size_t ws_size,
                              hipStream_t stream){
  const float* h   = (const float*)d_in[0];
  const int*   adj = (const int*)d_in[1];
  const float* W   = (const float*)d_in[2];
  const float* a   = (const float*)d_in[3];
  float* out = (float*)d_out;
  char* ws = (char*)d_ws;

  unsigned short* Bsw = (unsigned short*)ws;             // 2 MB
  float* s1L = (float*)(ws + (size_t)(6u<<20));          // 32 KB
  float* s2L = (float*)(ws + (size_t)(6u<<20) + 32768);  // 32 KB
  float* M2L = (float*)(ws + (size_t)(6u<<20) + 65536);  // 4 B
  float* denomp  = (float*)(ws + (size_t)(7u<<20));      // njc*32 KB (<=512KB)
  float* partial = (float*)(ws + (size_t)(8u<<20));      // njc*4 MB

  size_t chunk = (size_t)N * FD * sizeof(float);         // 4 MB
  int njc = 1;
  if (ws_size > ((size_t)(8u<<20))){
    size_t m = (ws_size - (size_t)(8u<<20)) / chunk;
    njc = (m >= 16) ? 16 : (m >= 8) ? 8 : (m >= 4) ? 4 : (m >= 2) ? 2 : 1;
  }

  hipLaunchKernelGGL(k12_wh, dim3(256), dim3(256), 0, stream, h, W, a, Bsw, s1L, s2L);
  hipLaunchKernelGGL(k3_max, dim3(1),   dim3(256), 0, stream, s2L, M2L);
  hipLaunchKernelGGL(k4_flash, dim3(64, njc), dim3(256), 0, stream,
                     adj, Bsw, s1L, s2L, M2L, partial, denomp, njc);
  hipLaunchKernelGGL(k5_fin, dim3(N*FD/256), dim3(256), 0, stream, partial, denomp, out, njc);
}

// Round 6
// 402.348 us; speedup vs baseline: 1.2167x; 1.0860x over previous
//
#include <hip/hip_runtime.h>
#include <hip/hip_bf16.h>

#define N 8192
#define FD 128
#define LOG2E 1.4426950408889634f

typedef __attribute__((ext_vector_type(4))) float f4;
typedef __attribute__((ext_vector_type(4))) int i32x4;
typedef __attribute__((ext_vector_type(4))) unsigned int u32x4;
typedef __attribute__((ext_vector_type(8))) __bf16 bf16x8;

__device__ __forceinline__ unsigned short bfbits(float x){
  __bf16 b = (__bf16)x;
  return __builtin_bit_cast(unsigned short, b);
}

// ---- K12: Wh = h @ W (f32) + Bsw (MFMA-B-swizzled bf16) + fused s1L/s2L tail ----
// Bsw flat layout: elem(jblk, n, lane, e) at ((jblk*8+n)*64 + lane)*8 + e
//   holds bf16( Wh[jblk*32 + (lane>>4)*8 + e][n*16 + (lane&15)] )
__global__ __launch_bounds__(256) void k12_wh(const float* __restrict__ h,
                                              const float* __restrict__ W,
                                              const float* __restrict__ a,
                                              unsigned short* __restrict__ Bsw,
                                              float* __restrict__ s1L,
                                              float* __restrict__ s2L){
  __shared__ float Wl[64*128];
  __shared__ float hT[128*33];
  int t = threadIdx.x;
  int i0 = blockIdx.x * 32;
  {
    int r  = t >> 3;
    int k0 = (t & 7) * 16;
    const f4* src = (const f4*)&h[(size_t)(i0 + r)*FD + k0];
    #pragma unroll
    for (int q = 0; q < 4; ++q){
      f4 v = src[q];
      #pragma unroll
      for (int e = 0; e < 4; ++e) hT[(k0 + q*4 + e)*33 + r] = v[e];
    }
  }
  int f0 = (t & 31) * 4;
  int r0 = (t >> 5) * 4;
  float acc[4][4] = {};
  for (int half = 0; half < 2; ++half){
    __syncthreads();
    #pragma unroll
    for (int v = 0; v < 8; ++v){
      int idx = (v*256 + t)*4;
      *(f4*)&Wl[idx] = *(const f4*)&W[half*8192 + idx];
    }
    __syncthreads();
    for (int k2 = 0; k2 < 64; ++k2){
      f4 wv = *(const f4*)&Wl[k2*FD + f0];
      f4 hv = *(const f4*)&hT[(half*64 + k2)*33 + r0];
      #pragma unroll
      for (int ri = 0; ri < 4; ++ri)
        #pragma unroll
        for (int fi = 0; fi < 4; ++fi)
          acc[ri][fi] = __builtin_fmaf(hv[ri], wv[fi], acc[ri][fi]);
    }
  }
  int jblk = blockIdx.x;
  int n  = f0 >> 4;
  int fl = f0 & 15;
  #pragma unroll
  for (int ri = 0; ri < 4; ++ri){
    int k = r0 + ri;
    size_t base = (((size_t)jblk*8 + n)*64 + ((k>>3)<<4))*8 + (k&7);
    #pragma unroll
    for (int fi = 0; fi < 4; ++fi)
      Bsw[base + (size_t)(fl + fi)*8] = bfbits(acc[ri][fi]);
  }
  f4 a1v = *(const f4*)&a[f0];
  f4 a2v = *(const f4*)&a[FD + f0];
  float p1[4], p2[4];
  #pragma unroll
  for (int ri = 0; ri < 4; ++ri){
    p1[ri] = 0.f; p2[ri] = 0.f;
    #pragma unroll
    for (int fi = 0; fi < 4; ++fi){
      p1[ri] = __builtin_fmaf(acc[ri][fi], a1v[fi], p1[ri]);
      p2[ri] = __builtin_fmaf(acc[ri][fi], a2v[fi], p2[ri]);
    }
  }
  #pragma unroll
  for (int d = 1; d < 32; d <<= 1){
    #pragma unroll
    for (int ri = 0; ri < 4; ++ri){
      p1[ri] += __shfl_xor(p1[ri], d, 32);
      p2[ri] += __shfl_xor(p2[ri], d, 32);
    }
  }
  if ((t & 31) == 0){
    #pragma unroll
    for (int ri = 0; ri < 4; ++ri){
      s1L[i0 + r0 + ri] = p1[ri] * LOG2E;
      s2L[i0 + r0 + ri] = p2[ri] * LOG2E;
    }
  }
}

// ---------------- K3: M2L = max(s2L) ----------------
__global__ __launch_bounds__(256) void k3_max(const float* __restrict__ s2L,
                                              float* __restrict__ M2L){
  __shared__ float red[4];
  int t = threadIdx.x;
  float m = -3.0e38f;
  for (int i = t; i < N; i += 256) m = fmaxf(m, s2L[i]);
  #pragma unroll
  for (int d = 1; d < 64; d <<= 1) m = fmaxf(m, __shfl_xor(m, d, 64));
  if ((t & 63) == 0) red[t >> 6] = m;
  __syncthreads();
  if (t == 0) *M2L = fmaxf(fmaxf(red[0], red[1]), fmaxf(red[2], red[3]));
}

// -------- K4 v5: double-buffered software-pipelined macro GEMM (T3 2-phase) ----
// Block = 256 thr (4 waves), 128 rows x one j-chunk. LDS dbuf: stage macro m+1
// (async Bsw global_load_lds + coalesced adj->regs) BEFORE computing macro m;
// pack masks after compute; ONE barrier per macro. XCD-aligned j-chunks
// (y = bid&7) keep each XCD's Bsw slice (256KB) L2-resident.
__global__ __launch_bounds__(256,2) void k4_flash(const int* __restrict__ adj,
    const unsigned short* __restrict__ Bsw,
    const float* __restrict__ s1L, const float* __restrict__ s2L,
    const float* __restrict__ M2p,
    float* __restrict__ partial, float* __restrict__ denomp, int njc){
  __shared__ __align__(16) unsigned char bswl[2][32768];
  __shared__ __align__(16) unsigned char mknib[2][128*32];
  __shared__ __align__(16) float s2l[2][128];
  int t = threadIdx.x;
  int wv = t >> 6, lane = t & 63;
  int lrow = lane & 15, lgrp = lane >> 4;
  int bid = blockIdx.x;
  int y  = bid & (njc - 1);        // njc is a power of 2; =8 aligns with 8 XCDs
  int bx = bid / njc;
  int jlen = N / njc;
  int jstart = y * jlen;
  int nmac = jlen >> 7;
  float M2 = *M2p;
  int i0w = bx*128 + wv*32;
  float s1a = s1L[i0w + lrow], s1b = s1L[i0w + 16 + lrow];
  float ea = s1a + M2, eb = s1b + M2;
  float maL = fmaxf(ea, 0.2f*ea);
  float mbL = fmaxf(eb, 0.2f*eb);

  f4 acc[2][8]; f4 accd[2];
  #pragma unroll
  for (int x = 0; x < 2; ++x){
    accd[x] = (f4){0.f,0.f,0.f,0.f};
    #pragma unroll
    for (int n = 0; n < 8; ++n) acc[x][n] = (f4){0.f,0.f,0.f,0.f};
  }
  u32x4 onesbits = (u32x4){0x3F803F80u,0x3F803F80u,0x3F803F80u,0x3F803F80u};
  bf16x8 ones = __builtin_bit_cast(bf16x8, onesbits);

  const i32x4* adj4 = (const i32x4*)adj;
  int sr2 = lane >> 5;                 // staging row parity
  int sj  = lane & 31;                 // 4-int group within 128-j macro
  size_t abase = ((size_t)(bx*128 + wv*32 + sr2) * N) >> 2;   // i32x4 units

  i32x4 st[16];

  // ---- stage helpers (inlined by hand) ----
  // Bsw async stage for macro jb0 into buffer b
  #define STAGE_BSW(jb0, b) do {                                               \
    const unsigned int* bg = (const unsigned int*)(Bsw + (size_t)((jb0) >> 5) * 4096); \
    _Pragma("unroll")                                                          \
    for (int q = 0; q < 8; ++q){                                               \
      int chunk = q*4 + wv;                                                    \
      __builtin_amdgcn_global_load_lds(                                        \
        (const __attribute__((address_space(1))) unsigned int*)(bg + (size_t)(chunk*64 + lane)*4), \
        (__attribute__((address_space(3))) unsigned int*)(&bswl[b][0] + chunk*1024), \
        16, 0, 0);                                                             \
    }                                                                          \
  } while(0)

  #define STAGE_ADJ(jb0) do {                                                  \
    size_t ab = abase + (size_t)((jb0) >> 2) + sj;                             \
    _Pragma("unroll")                                                          \
    for (int e = 0; e < 16; ++e) st[e] = adj4[ab + (size_t)e * 4096];          \
  } while(0)

  #define PACK_MASKS(b) do {                                                   \
    _Pragma("unroll")                                                          \
    for (int e = 0; e < 16; ++e){                                              \
      unsigned nib = (st[e][0] != 0 ? 1u : 0u) | (st[e][1] != 0 ? 2u : 0u)     \
                   | (st[e][2] != 0 ? 4u : 0u) | (st[e][3] != 0 ? 8u : 0u);    \
      int rloc = wv*32 + e*2 + sr2;                                            \
      mknib[b][rloc*32 + sj] = (unsigned char)nib;                             \
    }                                                                          \
  } while(0)

  // ---- prologue: stage macro 0 into buf 0 ----
  int buf = 0;
  STAGE_BSW(jstart, 0);
  STAGE_ADJ(jstart);
  PACK_MASKS(0);
  if (t < 32) *(f4*)&s2l[0][t*4] = *(const f4*)&s2L[jstart + t*4];
  __syncthreads();

  for (int m = 0; m < nmac; ++m){
    int jb0 = jstart + m*128;
    // ---- issue next macro's stage BEFORE compute (pipeline) ----
    if (m + 1 < nmac){
      STAGE_BSW(jb0 + 128, buf ^ 1);
      STAGE_ADJ(jb0 + 128);
    }
    // ---- compute current macro from LDS buf ----
    #pragma unroll
    for (int js = 0; js < 4; ++js){
      int jo = js*32 + lgrp*8;
      f4 ya = *(const f4*)&s2l[buf][jo];
      f4 yb = *(const f4*)&s2l[buf][jo+4];
      int gb = (js*4 + lgrp)*2;
      unsigned short ua = *(const unsigned short*)&mknib[buf][(wv*32 + lrow)*32 + gb];
      unsigned short ub = *(const unsigned short*)&mknib[buf][(wv*32 + 16 + lrow)*32 + gb];
      unsigned mba = (ua & 0xFu) | ((ua >> 4) & 0xF0u);
      unsigned mbb = (ub & 0xFu) | ((ub >> 4) & 0xF0u);
      bf16x8 fa, fb;
      #pragma unroll
      for (int e = 0; e < 8; ++e){
        float sjv = (e < 4) ? ya[e] : yb[e-4];
        float xa = s1a + sjv,            xb = s1b + sjv;
        float la = fmaxf(xa, 0.2f*xa),   lb = fmaxf(xb, 0.2f*xb);
        float pa = ((mba>>e)&1u) ? __builtin_amdgcn_exp2f(la - maL) : 0.f;
        float pb = ((mbb>>e)&1u) ? __builtin_amdgcn_exp2f(lb - mbL) : 0.f;
        fa[e] = (__bf16)pa; fb[e] = (__bf16)pb;
      }
      accd[0] = __builtin_amdgcn_mfma_f32_16x16x32_bf16(fa, ones, accd[0], 0, 0, 0);
      accd[1] = __builtin_amdgcn_mfma_f32_16x16x32_bf16(fb, ones, accd[1], 0, 0, 0);
      {
        u32x4 b0[4];
        #pragma unroll
        for (int n = 0; n < 4; ++n)
          b0[n] = *(const u32x4*)&bswl[buf][((js*8 + n)*64 + lane)*16];
        #pragma unroll
        for (int n = 0; n < 4; ++n){
          bf16x8 bb = __builtin_bit_cast(bf16x8, b0[n]);
          acc[0][n] = __builtin_amdgcn_mfma_f32_16x16x32_bf16(fa, bb, acc[0][n], 0, 0, 0);
          acc[1][n] = __builtin_amdgcn_mfma_f32_16x16x32_bf16(fb, bb, acc[1][n], 0, 0, 0);
        }
      }
      {
        u32x4 b1[4];
        #pragma unroll
        for (int n = 0; n < 4; ++n)
          b1[n] = *(const u32x4*)&bswl[buf][((js*8 + 4 + n)*64 + lane)*16];
        #pragma unroll
        for (int n = 0; n < 4; ++n){
          bf16x8 bb = __builtin_bit_cast(bf16x8, b1[n]);
          acc[0][4+n] = __builtin_amdgcn_mfma_f32_16x16x32_bf16(fa, bb, acc[0][4+n], 0, 0, 0);
          acc[1][4+n] = __builtin_amdgcn_mfma_f32_16x16x32_bf16(fb, bb, acc[1][4+n], 0, 0, 0);
        }
      }
    }
    // ---- land next macro's masks/s2 into the other buffer, then one barrier ----
    if (m + 1 < nmac){
      PACK_MASKS(buf ^ 1);
      if (t < 32) *(f4*)&s2l[buf ^ 1][t*4] = *(const f4*)&s2L[jb0 + 128 + t*4];
    }
    __syncthreads();   // compiler emits vmcnt(0) lgkmcnt(0) drain: Bsw GLDS landed
    buf ^= 1;
  }

  if (lrow == 0){
    #pragma unroll
    for (int x = 0; x < 2; ++x)
      #pragma unroll
      for (int r = 0; r < 4; ++r)
        denomp[(size_t)y*N + i0w + x*16 + lgrp*4 + r] = accd[x][r];
  }
  float* pb = partial + (size_t)y * N * FD;
  #pragma unroll
  for (int x = 0; x < 2; ++x)
    #pragma unroll
    for (int n = 0; n < 8; ++n)
      #pragma unroll
      for (int r = 0; r < 4; ++r)
        pb[(size_t)(i0w + x*16 + lgrp*4 + r)*FD + n*16 + lrow] = acc[x][n][r];
}

// ---------------- K5: combine partials, divide ----------------
__global__ __launch_bounds__(256) void k5_fin(const float* __restrict__ partial,
    const float* __restrict__ denomp, float* __restrict__ out, int njc){
  int g = blockIdx.x*256 + threadIdx.x;
  int i = g >> 7;
  float num = 0.f, den = 0.f;
  for (int c = 0; c < njc; ++c) num += partial[(size_t)c*N*FD + g];
  for (int c = 0; c < njc; ++c) den += denomp[(size_t)c*N + i];
  out[g] = num / den;
}

extern "C" void kernel_launch(void* const* d_in, const int* in_sizes, int n_in,
                              void* d_out, int out_size, void* d_ws, size_t ws_size,
                              hipStream_t stream){
  const float* h   = (const float*)d_in[0];
  const int*   adj = (const int*)d_in[1];
  const float* W   = (const float*)d_in[2];
  const float* a   = (const float*)d_in[3];
  float* out = (float*)d_out;
  char* ws = (char*)d_ws;

  unsigned short* Bsw = (unsigned short*)ws;             // 2 MB
  float* s1L = (float*)(ws + (size_t)(6u<<20));          // 32 KB
  float* s2L = (float*)(ws + (size_t)(6u<<20) + 32768);  // 32 KB
  float* M2L = (float*)(ws + (size_t)(6u<<20) + 65536);  // 4 B
  float* denomp  = (float*)(ws + (size_t)(7u<<20));      // njc*32 KB
  float* partial = (float*)(ws + (size_t)(8u<<20));      // njc*4 MB

  size_t chunk = (size_t)N * FD * sizeof(float);         // 4 MB
  int njc = 1;
  if (ws_size > ((size_t)(8u<<20))){
    size_t m = (ws_size - (size_t)(8u<<20)) / chunk;
    njc = (m >= 8) ? 8 : (m >= 4) ? 4 : (m >= 2) ? 2 : 1;
  }

  hipLaunchKernelGGL(k12_wh, dim3(256), dim3(256), 0, stream, h, W, a, Bsw, s1L, s2L);
  hipLaunchKernelGGL(k3_max, dim3(1),   dim3(256), 0, stream, s2L, M2L);
  hipLaunchKernelGGL(k4_flash, dim3(64*njc), dim3(256), 0, stream,
                     adj, Bsw, s1L, s2L, M2L, partial, denomp, njc);
  hipLaunchKernelGGL(k5_fin, dim3(N*FD/256), dim3(256), 0, stream, partial, denomp, out, njc);
}